// Round 19
// baseline (144.341 us; speedup 1.0000x reference)
//
#include <hip/hip_runtime.h>

// Problem constants (from reference)
constexpr int B  = 8;
constexpr int T  = 256;
constexpr int U1 = 65;
constexpr int DK = 640;    // D_ENC == D_pred
constexpr int V  = 1024;

constexpr int M_ENC  = B * T;    // 2048
constexpr int M_PRED = B * U1;   // 520

constexpr int NKS  = DK / 32;    // 20 k-steps
constexpr int RT_E = M_ENC / 16; // 128 A row-tiles (enc)
constexpr int RT_P = 36;         // pred row-tiles padded (576 rows >= 520)
constexpr int CT   = V / 16;     // 64 B col-tiles

typedef float  f32x4  __attribute__((ext_vector_type(4)));
typedef short  short8 __attribute__((ext_vector_type(8)));
typedef unsigned short u16x4 __attribute__((ext_vector_type(4)));

__device__ __forceinline__ short f2bf(float f) {
    union { float f; unsigned u; } x; x.f = f;
    unsigned r = x.u + 0x7fffu + ((x.u >> 16) & 1u);
    return (short)(r >> 16);
}
__device__ __forceinline__ f32x4 bf4_to_f32(u16x4 s) {
    f32x4 o;
    union { unsigned u; float f; } x;
    x.u = ((unsigned)s[0]) << 16; o[0] = x.f;
    x.u = ((unsigned)s[1]) << 16; o[1] = x.f;
    x.u = ((unsigned)s[2]) << 16; o[2] = x.f;
    x.u = ((unsigned)s[3]) << 16; o[3] = x.f;
    return o;
}

// ---------------------------------------------------------------------------
// prep: emit MFMA-fragment-major packed operands (frozen from R14).
// ---------------------------------------------------------------------------
constexpr int NB_AE = RT_E * NKS * 64 / 256;  // 640 blocks
constexpr int NB_AP = RT_P * NKS * 64 / 256;  // 180
constexpr int NB_BE = CT   * NKS * 64 / 256;  // 320
constexpr int NB_BP = NB_BE;                  // 320

__global__ __launch_bounds__(256) void prep_kernel(
    const float* __restrict__ enc, const float* __restrict__ pred,
    const float* __restrict__ W,
    short* __restrict__ Apack_e, short* __restrict__ Apack_p,
    short* __restrict__ Bpack_e, short* __restrict__ Bpack_p)
{
    const int bid = blockIdx.x;
    const int tid = threadIdx.x;

    if (bid < NB_AE) {                     // ---- A-pack enc ----
        const int chunk = bid * 256 + tid;
        const int l  = chunk & 63;
        const int ks = (chunk >> 6) % NKS;
        const int rt = chunk / (64 * NKS);
        const int row = rt * 16 + (l & 15);
        const float* src = enc + (size_t)row * DK + ks * 32 + (l >> 4) * 8;
        const f32x4 x = *reinterpret_cast<const f32x4*>(src);
        const f32x4 y = *reinterpret_cast<const f32x4*>(src + 4);
        short8 s;
        s[0]=f2bf(x[0]); s[1]=f2bf(x[1]); s[2]=f2bf(x[2]); s[3]=f2bf(x[3]);
        s[4]=f2bf(y[0]); s[5]=f2bf(y[1]); s[6]=f2bf(y[2]); s[7]=f2bf(y[3]);
        *reinterpret_cast<short8*>(Apack_e + (size_t)chunk * 8) = s;
    } else if (bid < NB_AE + NB_AP) {      // ---- A-pack pred (zero-padded) ----
        const int chunk = (bid - NB_AE) * 256 + tid;
        const int l  = chunk & 63;
        const int ks = (chunk >> 6) % NKS;
        const int rt = chunk / (64 * NKS);
        const int row = rt * 16 + (l & 15);
        short8 s;
        if (row < M_PRED) {
            const float* src = pred + (size_t)row * DK + ks * 32 + (l >> 4) * 8;
            const f32x4 x = *reinterpret_cast<const f32x4*>(src);
            const f32x4 y = *reinterpret_cast<const f32x4*>(src + 4);
            s[0]=f2bf(x[0]); s[1]=f2bf(x[1]); s[2]=f2bf(x[2]); s[3]=f2bf(x[3]);
            s[4]=f2bf(y[0]); s[5]=f2bf(y[1]); s[6]=f2bf(y[2]); s[7]=f2bf(y[3]);
        } else {
            #pragma unroll
            for (int j = 0; j < 8; ++j) s[j] = 0;
        }
        *reinterpret_cast<short8*>(Apack_p + (size_t)chunk * 8) = s;
    } else {                               // ---- B-pack enc / pred ----
        const bool isE = (bid < NB_AE + NB_AP + NB_BE);
        const int  base = isE ? (NB_AE + NB_AP) : (NB_AE + NB_AP + NB_BE);
        short* Bp = isE ? Bpack_e : Bpack_p;
        const int kofs = isE ? 0 : DK;
        const int chunk = (bid - base) * 256 + tid;
        const int l  = chunk & 63;
        const int ks = (chunk >> 6) % NKS;
        const int ct = chunk / (64 * NKS);
        const int v  = ct * 16 + (l & 15);
        const int k0 = kofs + ks * 32 + (l >> 4) * 8;
        short8 s;
        #pragma unroll
        for (int j = 0; j < 8; ++j)
            s[j] = f2bf(W[(size_t)(k0 + j) * V + v]);
        *reinterpret_cast<short8*>(Bp + (size_t)chunk * 8) = s;
    }
}

// ---------------------------------------------------------------------------
// pred GEMM (frozen from R14): 144 blocks, writes pred_proj (bf16, +bias).
// ---------------------------------------------------------------------------
constexpr int NB_GP = (RT_P / 4) * 16;       // 144

__global__ __launch_bounds__(256) void gemm_pred_kernel(
    const short* __restrict__ Apack_p, const short* __restrict__ Bpack_p,
    const float* __restrict__ bias, short* __restrict__ pred_proj)
{
    const int rb = blockIdx.x >> 4;
    const int cb = blockIdx.x & 15;

    const int wid  = threadIdx.x >> 6;
    const int lane = threadIdx.x & 63;
    const int wr   = wid >> 1, wc = wid & 1;
    const int m    = lane & 15, g = lane >> 4;

    const int rt0 = rb * 4 + wr * 2;
    const int ct0 = cb * 4 + wc * 2;

    const short* a0p = Apack_p + ((size_t)rt0 * NKS) * 512 + lane * 8;
    const short* a1p = a0p + (size_t)NKS * 512;
    const short* b0p = Bpack_p + ((size_t)ct0 * NKS) * 512 + lane * 8;
    const short* b1p = b0p + (size_t)NKS * 512;

    f32x4 z4; z4[0]=z4[1]=z4[2]=z4[3]=0.f;
    f32x4 acc00 = z4, acc01 = z4, acc10 = z4, acc11 = z4;

    #pragma unroll 4
    for (int ks = 0; ks < NKS; ++ks) {
        const size_t o = (size_t)ks * 512;
        const short8 a0 = *reinterpret_cast<const short8*>(a0p + o);
        const short8 a1 = *reinterpret_cast<const short8*>(a1p + o);
        const short8 b0 = *reinterpret_cast<const short8*>(b0p + o);
        const short8 b1 = *reinterpret_cast<const short8*>(b1p + o);
        acc00 = __builtin_amdgcn_mfma_f32_16x16x32_bf16(a0, b0, acc00, 0, 0, 0);
        acc01 = __builtin_amdgcn_mfma_f32_16x16x32_bf16(a0, b1, acc01, 0, 0, 0);
        acc10 = __builtin_amdgcn_mfma_f32_16x16x32_bf16(a1, b0, acc10, 0, 0, 0);
        acc11 = __builtin_amdgcn_mfma_f32_16x16x32_bf16(a1, b1, acc11, 0, 0, 0);
    }

    #pragma unroll
    for (int nt = 0; nt < 2; ++nt) {
        const int col = (ct0 + nt) * 16 + m;
        const float bv = bias[col];
        #pragma unroll
        for (int mt = 0; mt < 2; ++mt) {
            const f32x4 a = nt ? (mt ? acc11 : acc01) : (mt ? acc10 : acc00);
            #pragma unroll
            for (int q = 0; q < 4; ++q) {
                const int row = (rt0 + mt) * 16 + g * 4 + q;
                if (row < M_PRED)
                    pred_proj[(size_t)row * V + col] = f2bf(a[q] + bv);
            }
        }
    }
}

// ---------------------------------------------------------------------------
// FUSED v2 (R19): enc-GEMM + broadcast write.
// Grid: 128 row-tiles x 4 col-parts (256 cols) = 512 blocks, 256 thr.
// GEMM: wave w owns 16x64 (4 col-tiles), 1 A-load + 4 B-loads + 4 MFMA/kstep.
// e via LDS (8KB) once for the layout transpose. Write phase: thread
// c4 = tid&63 -> wave stores 1KB contiguous bursts (R16-proven); thread owns
// 4 rows at same c4 -> p loaded once per u from global (L2-broadcast).
// ---------------------------------------------------------------------------
constexpr int NB_F = RT_E * 4;   // 512

__global__ __launch_bounds__(256) void fused_kernel(
    const short* __restrict__ Apack_e, const short* __restrict__ Bpack_e,
    const short* __restrict__ pred_proj, float* __restrict__ out)
{
    __shared__ short e_s[16 * 256];      // 8 KB

    const int rt   = blockIdx.x >> 2;    // 0..127
    const int cp   = blockIdx.x & 3;     // 0..3
    const int b    = rt >> 4;
    const int col0 = cp * 256;
    const int tid  = threadIdx.x;

    // ---- GEMM phase ----
    const int wid  = tid >> 6;
    const int lane = tid & 63;
    const int m    = lane & 15, g = lane >> 4;

    const short* ap = Apack_e + ((size_t)rt * NKS) * 512 + lane * 8;
    const int ct0   = cp * 16 + wid * 4;
    const short* bp = Bpack_e + ((size_t)ct0 * NKS) * 512 + lane * 8;

    f32x4 z4; z4[0]=z4[1]=z4[2]=z4[3]=0.f;
    f32x4 acc[4];
    #pragma unroll
    for (int t = 0; t < 4; ++t) acc[t] = z4;

    #pragma unroll 4
    for (int ks = 0; ks < NKS; ++ks) {
        const size_t o = (size_t)ks * 512;
        const short8 a = *reinterpret_cast<const short8*>(ap + o);
        #pragma unroll
        for (int t = 0; t < 4; ++t) {
            const short8 bt = *reinterpret_cast<const short8*>(
                bp + (size_t)t * NKS * 512 + o);
            acc[t] = __builtin_amdgcn_mfma_f32_16x16x32_bf16(a, bt, acc[t], 0, 0, 0);
        }
    }

    // ---- acc -> LDS bf16 (same numerics as old enc_proj roundtrip) ----
    #pragma unroll
    for (int t = 0; t < 4; ++t) {
        const int col = wid * 64 + t * 16 + m;          // within 256
        #pragma unroll
        for (int q = 0; q < 4; ++q)
            e_s[(g * 4 + q) * 256 + col] = f2bf(acc[t][q]);
    }
    __syncthreads();

    // ---- write phase ----
    const int c4 = tid & 63;             // 16B col chunk (0..63) -> 1KB/wave
    const int r4 = tid >> 6;             // 0..3; rows r4, r4+4, r4+8, r4+12

    f32x4 e[4];
    #pragma unroll
    for (int i = 0; i < 4; ++i)
        e[i] = bf4_to_f32(*reinterpret_cast<const u16x4*>(
            e_s + (r4 + i * 4) * 256 + c4 * 4));

    const short* p = pred_proj + (size_t)b * U1 * V + col0 + c4 * 4;
    float* orow[4];
    #pragma unroll
    for (int i = 0; i < 4; ++i)
        orow[i] = out + ((size_t)(rt * 16 + r4 + i * 4) * U1) * V + col0 + c4 * 4;

    for (int u0 = 0; u0 < 64; u0 += 8) {
        u16x4 pv[8];
        #pragma unroll
        for (int j = 0; j < 8; ++j)
            pv[j] = *reinterpret_cast<const u16x4*>(p + (size_t)(u0 + j) * V);
        #pragma unroll
        for (int j = 0; j < 8; ++j) {
            const f32x4 pf = bf4_to_f32(pv[j]);
            #pragma unroll
            for (int i = 0; i < 4; ++i)
                *reinterpret_cast<f32x4*>(orow[i] + (size_t)(u0 + j) * V) = e[i] + pf;
        }
    }
    {   // tail u = 64
        const f32x4 pf = bf4_to_f32(
            *reinterpret_cast<const u16x4*>(p + (size_t)64 * V));
        #pragma unroll
        for (int i = 0; i < 4; ++i)
            *reinterpret_cast<f32x4*>(orow[i] + (size_t)64 * V) = e[i] + pf;
    }
}

extern "C" void kernel_launch(void* const* d_in, const int* in_sizes, int n_in,
                              void* d_out, int out_size, void* d_ws, size_t ws_size,
                              hipStream_t stream)
{
    const float* enc  = (const float*)d_in[0];   // (8,256,640)
    const float* pred = (const float*)d_in[1];   // (8,65,640)
    const float* W    = (const float*)d_in[2];   // (1280,1024)
    const float* bias = (const float*)d_in[3];   // (1024,)
    float* out = (float*)d_out;                  // (8,256,65,1024)

    // ws layout in shorts (6.5 MB; ws ≈ 2.18 GB per fill-dispatch evidence).
    short* Apack_e  = (short*)d_ws;                                   // 1,310,720
    short* Apack_p  = Apack_e + (size_t)RT_E * NKS * 512;             //   368,640
    short* Bpack_e  = Apack_p + (size_t)RT_P * NKS * 512;             //   655,360
    short* Bpack_p  = Bpack_e + (size_t)CT * NKS * 512;               //   655,360
    short* pred_proj = Bpack_p + (size_t)CT * NKS * 512;              //   532,480

    prep_kernel<<<NB_AE + NB_AP + NB_BE + NB_BP, 256, 0, stream>>>(
        enc, pred, W, Apack_e, Apack_p, Bpack_e, Bpack_p);

    gemm_pred_kernel<<<NB_GP, 256, 0, stream>>>(
        Apack_p, Bpack_p, bias, pred_proj);

    fused_kernel<<<NB_F, 256, 0, stream>>>(
        Apack_e, Bpack_e, pred_proj, out);
}

// Round 20
// 124.813 us; speedup vs baseline: 1.1565x; 1.1565x over previous
//
#include <hip/hip_runtime.h>

// Problem constants (from reference)
constexpr int B  = 8;
constexpr int T  = 256;
constexpr int U1 = 65;
constexpr int DK = 640;    // D_ENC == D_pred
constexpr int V  = 1024;

constexpr int M_ENC  = B * T;    // 2048
constexpr int M_PRED = B * U1;   // 520

constexpr int NKS  = DK / 32;    // 20 k-steps
constexpr int RT_E = M_ENC / 16; // 128 A row-tiles (enc)
constexpr int RT_P = 36;         // pred row-tiles padded (576 rows >= 520)
constexpr int CT   = V / 16;     // 64 B col-tiles

typedef float  f32x4  __attribute__((ext_vector_type(4)));
typedef short  short8 __attribute__((ext_vector_type(8)));
typedef unsigned short u16x4 __attribute__((ext_vector_type(4)));

__device__ __forceinline__ short f2bf(float f) {
    union { float f; unsigned u; } x; x.f = f;
    unsigned r = x.u + 0x7fffu + ((x.u >> 16) & 1u);
    return (short)(r >> 16);
}
__device__ __forceinline__ f32x4 bf4_to_f32(u16x4 s) {
    f32x4 o;
    union { unsigned u; float f; } x;
    x.u = ((unsigned)s[0]) << 16; o[0] = x.f;
    x.u = ((unsigned)s[1]) << 16; o[1] = x.f;
    x.u = ((unsigned)s[2]) << 16; o[2] = x.f;
    x.u = ((unsigned)s[3]) << 16; o[3] = x.f;
    return o;
}

// ---------------------------------------------------------------------------
// prep: emit MFMA-fragment-major packed operands (frozen from R14).
// ---------------------------------------------------------------------------
constexpr int NB_AE = RT_E * NKS * 64 / 256;  // 640 blocks
constexpr int NB_AP = RT_P * NKS * 64 / 256;  // 180
constexpr int NB_BE = CT   * NKS * 64 / 256;  // 320
constexpr int NB_BP = NB_BE;                  // 320

__global__ __launch_bounds__(256) void prep_kernel(
    const float* __restrict__ enc, const float* __restrict__ pred,
    const float* __restrict__ W,
    short* __restrict__ Apack_e, short* __restrict__ Apack_p,
    short* __restrict__ Bpack_e, short* __restrict__ Bpack_p)
{
    const int bid = blockIdx.x;
    const int tid = threadIdx.x;

    if (bid < NB_AE) {                     // ---- A-pack enc ----
        const int chunk = bid * 256 + tid;
        const int l  = chunk & 63;
        const int ks = (chunk >> 6) % NKS;
        const int rt = chunk / (64 * NKS);
        const int row = rt * 16 + (l & 15);
        const float* src = enc + (size_t)row * DK + ks * 32 + (l >> 4) * 8;
        const f32x4 x = *reinterpret_cast<const f32x4*>(src);
        const f32x4 y = *reinterpret_cast<const f32x4*>(src + 4);
        short8 s;
        s[0]=f2bf(x[0]); s[1]=f2bf(x[1]); s[2]=f2bf(x[2]); s[3]=f2bf(x[3]);
        s[4]=f2bf(y[0]); s[5]=f2bf(y[1]); s[6]=f2bf(y[2]); s[7]=f2bf(y[3]);
        *reinterpret_cast<short8*>(Apack_e + (size_t)chunk * 8) = s;
    } else if (bid < NB_AE + NB_AP) {      // ---- A-pack pred (zero-padded) ----
        const int chunk = (bid - NB_AE) * 256 + tid;
        const int l  = chunk & 63;
        const int ks = (chunk >> 6) % NKS;
        const int rt = chunk / (64 * NKS);
        const int row = rt * 16 + (l & 15);
        short8 s;
        if (row < M_PRED) {
            const float* src = pred + (size_t)row * DK + ks * 32 + (l >> 4) * 8;
            const f32x4 x = *reinterpret_cast<const f32x4*>(src);
            const f32x4 y = *reinterpret_cast<const f32x4*>(src + 4);
            s[0]=f2bf(x[0]); s[1]=f2bf(x[1]); s[2]=f2bf(x[2]); s[3]=f2bf(x[3]);
            s[4]=f2bf(y[0]); s[5]=f2bf(y[1]); s[6]=f2bf(y[2]); s[7]=f2bf(y[3]);
        } else {
            #pragma unroll
            for (int j = 0; j < 8; ++j) s[j] = 0;
        }
        *reinterpret_cast<short8*>(Apack_p + (size_t)chunk * 8) = s;
    } else {                               // ---- B-pack enc / pred ----
        const bool isE = (bid < NB_AE + NB_AP + NB_BE);
        const int  base = isE ? (NB_AE + NB_AP) : (NB_AE + NB_AP + NB_BE);
        short* Bp = isE ? Bpack_e : Bpack_p;
        const int kofs = isE ? 0 : DK;
        const int chunk = (bid - base) * 256 + tid;
        const int l  = chunk & 63;
        const int ks = (chunk >> 6) % NKS;
        const int ct = chunk / (64 * NKS);
        const int v  = ct * 16 + (l & 15);
        const int k0 = kofs + ks * 32 + (l >> 4) * 8;
        short8 s;
        #pragma unroll
        for (int j = 0; j < 8; ++j)
            s[j] = f2bf(W[(size_t)(k0 + j) * V + v]);
        *reinterpret_cast<short8*>(Bp + (size_t)chunk * 8) = s;
    }
}

// ---------------------------------------------------------------------------
// GEMM, both problems in one launch (frozen from R16): 656 blocks.
// ---------------------------------------------------------------------------
constexpr int NB_GE = (M_ENC / 64) * 16;     // 512
constexpr int NB_GP = (RT_P / 4) * 16;       // 144

__global__ __launch_bounds__(256) void gemm_kernel(
    const short* __restrict__ Apack_e, const short* __restrict__ Apack_p,
    const short* __restrict__ Bpack_e, const short* __restrict__ Bpack_p,
    const float* __restrict__ bias,
    short* __restrict__ enc_proj, short* __restrict__ pred_proj)
{
    const bool isE = (blockIdx.x < NB_GE);
    const int  lb  = isE ? blockIdx.x : blockIdx.x - NB_GE;
    const int  rb  = lb >> 4;
    const int  cb  = lb & 15;

    const short* Ap = isE ? Apack_e : Apack_p;
    const short* Bp = isE ? Bpack_e : Bpack_p;
    short* O        = isE ? enc_proj : pred_proj;
    const int M     = isE ? M_ENC : M_PRED;

    const int wid  = threadIdx.x >> 6;
    const int lane = threadIdx.x & 63;
    const int wr   = wid >> 1, wc = wid & 1;
    const int m    = lane & 15, g = lane >> 4;

    const int rt0 = rb * 4 + wr * 2;
    const int ct0 = cb * 4 + wc * 2;

    const short* a0p = Ap + ((size_t)rt0 * NKS) * 512 + lane * 8;
    const short* a1p = a0p + (size_t)NKS * 512;
    const short* b0p = Bp + ((size_t)ct0 * NKS) * 512 + lane * 8;
    const short* b1p = b0p + (size_t)NKS * 512;

    f32x4 z4; z4[0]=z4[1]=z4[2]=z4[3]=0.f;
    f32x4 acc00 = z4, acc01 = z4, acc10 = z4, acc11 = z4;

    #pragma unroll 4
    for (int ks = 0; ks < NKS; ++ks) {
        const size_t o = (size_t)ks * 512;
        const short8 a0 = *reinterpret_cast<const short8*>(a0p + o);
        const short8 a1 = *reinterpret_cast<const short8*>(a1p + o);
        const short8 b0 = *reinterpret_cast<const short8*>(b0p + o);
        const short8 b1 = *reinterpret_cast<const short8*>(b1p + o);
        acc00 = __builtin_amdgcn_mfma_f32_16x16x32_bf16(a0, b0, acc00, 0, 0, 0);
        acc01 = __builtin_amdgcn_mfma_f32_16x16x32_bf16(a0, b1, acc01, 0, 0, 0);
        acc10 = __builtin_amdgcn_mfma_f32_16x16x32_bf16(a1, b0, acc10, 0, 0, 0);
        acc11 = __builtin_amdgcn_mfma_f32_16x16x32_bf16(a1, b1, acc11, 0, 0, 0);
    }

    #pragma unroll
    for (int nt = 0; nt < 2; ++nt) {
        const int col = (ct0 + nt) * 16 + m;
        const float bv = isE ? 0.f : bias[col];
        #pragma unroll
        for (int mt = 0; mt < 2; ++mt) {
            const f32x4 a = nt ? (mt ? acc11 : acc01) : (mt ? acc10 : acc00);
            #pragma unroll
            for (int q = 0; q < 4; ++q) {
                const int row = (rt0 + mt) * 16 + g * 4 + q;
                if (row < M)
                    O[(size_t)row * V + col] = f2bf(a[q] + bv);
            }
        }
    }
}

// ---------------------------------------------------------------------------
// bcast (R16-proven best): 2 bt-rows/block, 1024 blocks, 8-deep p-load
// batches, temporal stores, bf16 reads, f32 out.
// ---------------------------------------------------------------------------
__global__ __launch_bounds__(256) void bcast_kernel(
    const short* __restrict__ enc_proj, const short* __restrict__ pred_proj,
    float* __restrict__ out)
{
    const int bt0 = blockIdx.x * 2;
    const int b   = bt0 >> 8;            // T = 256
    const int tid = threadIdx.x;

    const f32x4 e0 = bf4_to_f32(*reinterpret_cast<const u16x4*>(
        enc_proj + (size_t)bt0 * V + tid * 4));
    const f32x4 e1 = bf4_to_f32(*reinterpret_cast<const u16x4*>(
        enc_proj + (size_t)(bt0 + 1) * V + tid * 4));

    const short* p = pred_proj + (size_t)b * U1 * V + tid * 4;
    float* o0 = out + (size_t)bt0 * U1 * V;
    float* o1 = out + (size_t)(bt0 + 1) * U1 * V;

    for (int u0 = 0; u0 < 64; u0 += 8) {
        u16x4 pv[8];
        #pragma unroll
        for (int j = 0; j < 8; ++j)
            pv[j] = *reinterpret_cast<const u16x4*>(p + (size_t)(u0 + j) * V);
        #pragma unroll
        for (int j = 0; j < 8; ++j) {
            const f32x4 pf = bf4_to_f32(pv[j]);
            *(reinterpret_cast<f32x4*>(o0 + (size_t)(u0 + j) * V) + tid) = e0 + pf;
            *(reinterpret_cast<f32x4*>(o1 + (size_t)(u0 + j) * V) + tid) = e1 + pf;
        }
    }
    {   // tail u = 64
        const f32x4 pf = bf4_to_f32(
            *reinterpret_cast<const u16x4*>(p + (size_t)64 * V));
        *(reinterpret_cast<f32x4*>(o0 + (size_t)64 * V) + tid) = e0 + pf;
        *(reinterpret_cast<f32x4*>(o1 + (size_t)64 * V) + tid) = e1 + pf;
    }
}

extern "C" void kernel_launch(void* const* d_in, const int* in_sizes, int n_in,
                              void* d_out, int out_size, void* d_ws, size_t ws_size,
                              hipStream_t stream)
{
    const float* enc  = (const float*)d_in[0];   // (8,256,640)
    const float* pred = (const float*)d_in[1];   // (8,65,640)
    const float* W    = (const float*)d_in[2];   // (1280,1024)
    const float* bias = (const float*)d_in[3];   // (1024,)
    float* out = (float*)d_out;                  // (8,256,65,1024)

    // ws layout in shorts, all separate slots (10.70 MB; ws ≈ 2.18 GB).
    short* Apack_e  = (short*)d_ws;                                   // 1,310,720
    short* Apack_p  = Apack_e + (size_t)RT_E * NKS * 512;             //   368,640
    short* Bpack_e  = Apack_p + (size_t)RT_P * NKS * 512;             //   655,360
    short* Bpack_p  = Bpack_e + (size_t)CT * NKS * 512;               //   655,360
    short* enc_proj = Bpack_p + (size_t)CT * NKS * 512;               // 2,097,152
    short* pred_proj = enc_proj + (size_t)M_ENC * V;                  //   532,480

    prep_kernel<<<NB_AE + NB_AP + NB_BE + NB_BP, 256, 0, stream>>>(
        enc, pred, W, Apack_e, Apack_p, Bpack_e, Bpack_p);

    gemm_kernel<<<NB_GE + NB_GP, 256, 0, stream>>>(
        Apack_e, Apack_p, Bpack_e, Bpack_p, bias, enc_proj, pred_proj);

    bcast_kernel<<<M_ENC / 2, 256, 0, stream>>>(enc_proj, pred_proj, out);
}

// Round 21
// 121.843 us; speedup vs baseline: 1.1846x; 1.0244x over previous
//
#include <hip/hip_runtime.h>

// Problem constants (from reference)
constexpr int B  = 8;
constexpr int T  = 256;
constexpr int U1 = 65;
constexpr int DK = 640;    // D_ENC == D_pred
constexpr int V  = 1024;

constexpr int M_ENC  = B * T;    // 2048
constexpr int M_PRED = B * U1;   // 520

constexpr int NKS  = DK / 32;    // 20 k-steps
constexpr int RT_E = M_ENC / 16; // 128 A row-tiles (enc)
constexpr int RT_P = 36;         // pred row-tiles padded (576 rows >= 520)
constexpr int CT   = V / 16;     // 64 B col-tiles

typedef float  f32x4  __attribute__((ext_vector_type(4)));
typedef short  short8 __attribute__((ext_vector_type(8)));
typedef unsigned short u16x4 __attribute__((ext_vector_type(4)));

__device__ __forceinline__ short f2bf(float f) {
    union { float f; unsigned u; } x; x.f = f;
    unsigned r = x.u + 0x7fffu + ((x.u >> 16) & 1u);
    return (short)(r >> 16);
}
__device__ __forceinline__ f32x4 bf4_to_f32(u16x4 s) {
    f32x4 o;
    union { unsigned u; float f; } x;
    x.u = ((unsigned)s[0]) << 16; o[0] = x.f;
    x.u = ((unsigned)s[1]) << 16; o[1] = x.f;
    x.u = ((unsigned)s[2]) << 16; o[2] = x.f;
    x.u = ((unsigned)s[3]) << 16; o[3] = x.f;
    return o;
}

// ---------------------------------------------------------------------------
// prep: emit MFMA-fragment-major packed operands (frozen from R14).
// ---------------------------------------------------------------------------
constexpr int NB_AE = RT_E * NKS * 64 / 256;  // 640 blocks
constexpr int NB_AP = RT_P * NKS * 64 / 256;  // 180
constexpr int NB_BE = CT   * NKS * 64 / 256;  // 320
constexpr int NB_BP = NB_BE;                  // 320

__global__ __launch_bounds__(256) void prep_kernel(
    const float* __restrict__ enc, const float* __restrict__ pred,
    const float* __restrict__ W,
    short* __restrict__ Apack_e, short* __restrict__ Apack_p,
    short* __restrict__ Bpack_e, short* __restrict__ Bpack_p)
{
    const int bid = blockIdx.x;
    const int tid = threadIdx.x;

    if (bid < NB_AE) {                     // ---- A-pack enc ----
        const int chunk = bid * 256 + tid;
        const int l  = chunk & 63;
        const int ks = (chunk >> 6) % NKS;
        const int rt = chunk / (64 * NKS);
        const int row = rt * 16 + (l & 15);
        const float* src = enc + (size_t)row * DK + ks * 32 + (l >> 4) * 8;
        const f32x4 x = *reinterpret_cast<const f32x4*>(src);
        const f32x4 y = *reinterpret_cast<const f32x4*>(src + 4);
        short8 s;
        s[0]=f2bf(x[0]); s[1]=f2bf(x[1]); s[2]=f2bf(x[2]); s[3]=f2bf(x[3]);
        s[4]=f2bf(y[0]); s[5]=f2bf(y[1]); s[6]=f2bf(y[2]); s[7]=f2bf(y[3]);
        *reinterpret_cast<short8*>(Apack_e + (size_t)chunk * 8) = s;
    } else if (bid < NB_AE + NB_AP) {      // ---- A-pack pred (zero-padded) ----
        const int chunk = (bid - NB_AE) * 256 + tid;
        const int l  = chunk & 63;
        const int ks = (chunk >> 6) % NKS;
        const int rt = chunk / (64 * NKS);
        const int row = rt * 16 + (l & 15);
        short8 s;
        if (row < M_PRED) {
            const float* src = pred + (size_t)row * DK + ks * 32 + (l >> 4) * 8;
            const f32x4 x = *reinterpret_cast<const f32x4*>(src);
            const f32x4 y = *reinterpret_cast<const f32x4*>(src + 4);
            s[0]=f2bf(x[0]); s[1]=f2bf(x[1]); s[2]=f2bf(x[2]); s[3]=f2bf(x[3]);
            s[4]=f2bf(y[0]); s[5]=f2bf(y[1]); s[6]=f2bf(y[2]); s[7]=f2bf(y[3]);
        } else {
            #pragma unroll
            for (int j = 0; j < 8; ++j) s[j] = 0;
        }
        *reinterpret_cast<short8*>(Apack_p + (size_t)chunk * 8) = s;
    } else {                               // ---- B-pack enc / pred ----
        const bool isE = (bid < NB_AE + NB_AP + NB_BE);
        const int  base = isE ? (NB_AE + NB_AP) : (NB_AE + NB_AP + NB_BE);
        short* Bp = isE ? Bpack_e : Bpack_p;
        const int kofs = isE ? 0 : DK;
        const int chunk = (bid - base) * 256 + tid;
        const int l  = chunk & 63;
        const int ks = (chunk >> 6) % NKS;
        const int ct = chunk / (64 * NKS);
        const int v  = ct * 16 + (l & 15);
        const int k0 = kofs + ks * 32 + (l >> 4) * 8;
        short8 s;
        #pragma unroll
        for (int j = 0; j < 8; ++j)
            s[j] = f2bf(W[(size_t)(k0 + j) * V + v]);
        *reinterpret_cast<short8*>(Bp + (size_t)chunk * 8) = s;
    }
}

// ---------------------------------------------------------------------------
// GEMM, both problems in one launch (frozen from R16): 656 blocks.
// ---------------------------------------------------------------------------
constexpr int NB_GE = (M_ENC / 64) * 16;     // 512
constexpr int NB_GP = (RT_P / 4) * 16;       // 144

__global__ __launch_bounds__(256) void gemm_kernel(
    const short* __restrict__ Apack_e, const short* __restrict__ Apack_p,
    const short* __restrict__ Bpack_e, const short* __restrict__ Bpack_p,
    const float* __restrict__ bias,
    short* __restrict__ enc_proj, short* __restrict__ pred_proj)
{
    const bool isE = (blockIdx.x < NB_GE);
    const int  lb  = isE ? blockIdx.x : blockIdx.x - NB_GE;
    const int  rb  = lb >> 4;
    const int  cb  = lb & 15;

    const short* Ap = isE ? Apack_e : Apack_p;
    const short* Bp = isE ? Bpack_e : Bpack_p;
    short* O        = isE ? enc_proj : pred_proj;
    const int M     = isE ? M_ENC : M_PRED;

    const int wid  = threadIdx.x >> 6;
    const int lane = threadIdx.x & 63;
    const int wr   = wid >> 1, wc = wid & 1;
    const int m    = lane & 15, g = lane >> 4;

    const int rt0 = rb * 4 + wr * 2;
    const int ct0 = cb * 4 + wc * 2;

    const short* a0p = Ap + ((size_t)rt0 * NKS) * 512 + lane * 8;
    const short* a1p = a0p + (size_t)NKS * 512;
    const short* b0p = Bp + ((size_t)ct0 * NKS) * 512 + lane * 8;
    const short* b1p = b0p + (size_t)NKS * 512;

    f32x4 z4; z4[0]=z4[1]=z4[2]=z4[3]=0.f;
    f32x4 acc00 = z4, acc01 = z4, acc10 = z4, acc11 = z4;

    #pragma unroll 4
    for (int ks = 0; ks < NKS; ++ks) {
        const size_t o = (size_t)ks * 512;
        const short8 a0 = *reinterpret_cast<const short8*>(a0p + o);
        const short8 a1 = *reinterpret_cast<const short8*>(a1p + o);
        const short8 b0 = *reinterpret_cast<const short8*>(b0p + o);
        const short8 b1 = *reinterpret_cast<const short8*>(b1p + o);
        acc00 = __builtin_amdgcn_mfma_f32_16x16x32_bf16(a0, b0, acc00, 0, 0, 0);
        acc01 = __builtin_amdgcn_mfma_f32_16x16x32_bf16(a0, b1, acc01, 0, 0, 0);
        acc10 = __builtin_amdgcn_mfma_f32_16x16x32_bf16(a1, b0, acc10, 0, 0, 0);
        acc11 = __builtin_amdgcn_mfma_f32_16x16x32_bf16(a1, b1, acc11, 0, 0, 0);
    }

    #pragma unroll
    for (int nt = 0; nt < 2; ++nt) {
        const int col = (ct0 + nt) * 16 + m;
        const float bv = isE ? 0.f : bias[col];
        #pragma unroll
        for (int mt = 0; mt < 2; ++mt) {
            const f32x4 a = nt ? (mt ? acc11 : acc01) : (mt ? acc10 : acc00);
            #pragma unroll
            for (int q = 0; q < 4; ++q) {
                const int row = (rt0 + mt) * 16 + g * 4 + q;
                if (row < M)
                    O[(size_t)row * V + col] = f2bf(a[q] + bv);
            }
        }
    }
}

// ---------------------------------------------------------------------------
// bcast R21: R16 geometry (2 rows/block, 1024 blocks) + SOFTWARE-PIPELINED
// p-loads: batch k+1's 8 loads issue BEFORE batch k's 16 stores, so each
// wave's load latency hides under its own store issue (fill-kernel-like
// uninterrupted store stream). pvA/pvB statically selected (rule #20).
// ---------------------------------------------------------------------------
__global__ __launch_bounds__(256) void bcast_kernel(
    const short* __restrict__ enc_proj, const short* __restrict__ pred_proj,
    float* __restrict__ out)
{
    const int bt0 = blockIdx.x * 2;
    const int b   = bt0 >> 8;            // T = 256
    const int tid = threadIdx.x;

    const f32x4 e0 = bf4_to_f32(*reinterpret_cast<const u16x4*>(
        enc_proj + (size_t)bt0 * V + tid * 4));
    const f32x4 e1 = bf4_to_f32(*reinterpret_cast<const u16x4*>(
        enc_proj + (size_t)(bt0 + 1) * V + tid * 4));

    const short* p = pred_proj + (size_t)b * U1 * V + tid * 4;
    float* o0 = out + (size_t)bt0 * U1 * V;
    float* o1 = out + (size_t)(bt0 + 1) * U1 * V;

    u16x4 pvA[8], pvB[8];

    // preload batch 0 (u = 0..7)
    #pragma unroll
    for (int j = 0; j < 8; ++j)
        pvA[j] = *reinterpret_cast<const u16x4*>(p + (size_t)j * V);

    // 8 batches of 8 u's; fully unrolled so buffer selection is static.
    #pragma unroll
    for (int k = 0; k < 8; ++k) {
        const int u0 = k * 8;
        // issue next batch's loads first (hide latency under stores below)
        if (k < 7) {
            if ((k & 1) == 0) {
                #pragma unroll
                for (int j = 0; j < 8; ++j)
                    pvB[j] = *reinterpret_cast<const u16x4*>(
                        p + (size_t)(u0 + 8 + j) * V);
            } else {
                #pragma unroll
                for (int j = 0; j < 8; ++j)
                    pvA[j] = *reinterpret_cast<const u16x4*>(
                        p + (size_t)(u0 + 8 + j) * V);
            }
        }
        // stores for current batch
        #pragma unroll
        for (int j = 0; j < 8; ++j) {
            const u16x4 pv = ((k & 1) == 0) ? pvA[j] : pvB[j];
            const f32x4 pf = bf4_to_f32(pv);
            *(reinterpret_cast<f32x4*>(o0 + (size_t)(u0 + j) * V) + tid) = e0 + pf;
            *(reinterpret_cast<f32x4*>(o1 + (size_t)(u0 + j) * V) + tid) = e1 + pf;
        }
    }
    {   // tail u = 64
        const f32x4 pf = bf4_to_f32(
            *reinterpret_cast<const u16x4*>(p + (size_t)64 * V));
        *(reinterpret_cast<f32x4*>(o0 + (size_t)64 * V) + tid) = e0 + pf;
        *(reinterpret_cast<f32x4*>(o1 + (size_t)64 * V) + tid) = e1 + pf;
    }
}

extern "C" void kernel_launch(void* const* d_in, const int* in_sizes, int n_in,
                              void* d_out, int out_size, void* d_ws, size_t ws_size,
                              hipStream_t stream)
{
    const float* enc  = (const float*)d_in[0];   // (8,256,640)
    const float* pred = (const float*)d_in[1];   // (8,65,640)
    const float* W    = (const float*)d_in[2];   // (1280,1024)
    const float* bias = (const float*)d_in[3];   // (1024,)
    float* out = (float*)d_out;                  // (8,256,65,1024)

    // ws layout in shorts, all separate slots (10.70 MB; ws ≈ 2.18 GB).
    short* Apack_e  = (short*)d_ws;                                   // 1,310,720
    short* Apack_p  = Apack_e + (size_t)RT_E * NKS * 512;             //   368,640
    short* Bpack_e  = Apack_p + (size_t)RT_P * NKS * 512;             //   655,360
    short* Bpack_p  = Bpack_e + (size_t)CT * NKS * 512;               //   655,360
    short* enc_proj = Bpack_p + (size_t)CT * NKS * 512;               // 2,097,152
    short* pred_proj = enc_proj + (size_t)M_ENC * V;                  //   532,480

    prep_kernel<<<NB_AE + NB_AP + NB_BE + NB_BP, 256, 0, stream>>>(
        enc, pred, W, Apack_e, Apack_p, Bpack_e, Bpack_p);

    gemm_kernel<<<NB_GE + NB_GP, 256, 0, stream>>>(
        Apack_e, Apack_p, Bpack_e, Bpack_p, bias, enc_proj, pred_proj);

    bcast_kernel<<<M_ENC / 2, 256, 0, stream>>>(enc_proj, pred_proj, out);
}